// Round 4
// baseline (3970.090 us; speedup 1.0000x reference)
//
#include <hip/hip_runtime.h>

typedef unsigned int u32;
typedef unsigned long long u64;
typedef unsigned short u16;

#define M_ROWS 32768
#define DB 256
#define DIN 1024
#define KCODES 16384

// order-preserving fp32 -> u32 (finite values)
__device__ __forceinline__ u32 ford(float f) {
    u32 u = __float_as_uint(f);
    return (u & 0x80000000u) ? ~u : (u | 0x80000000u);
}
__device__ __forceinline__ u64 shfl_xor_u64(u64 v, int m) {
    u32 lo = (u32)v, hi = (u32)(v >> 32);
    lo = (u32)__shfl_xor((int)lo, m, 64);
    hi = (u32)__shfl_xor((int)hi, m, 64);
    return ((u64)hi << 32) | lo;
}

// C(f32)[M,N] = A(f32)[M,Kd] @ B(f32)[Kd,N] + bias(f32)[N]
// block tile 128x128, BK=16, thread tile 8x8, 256 threads.
__global__ __launch_bounds__(256)
void sgemm_f32(const float* __restrict__ A, int lda,
               const float* __restrict__ B, int ldb,
               const float* __restrict__ bias,
               float* __restrict__ C, int ldc, int Kd)
{
    __shared__ float As[16][132];
    __shared__ float Bs[16][132];
    const int t = threadIdx.x;
    const int w = t >> 6, lane = t & 63;
    // 8x8 lane grid per wave -> <=2-way LDS conflicts on frag reads
    const int tx = (lane & 7) | ((w & 1) << 3);
    const int ty = ((lane >> 3) & 7) | ((w >> 1) << 3);
    const int rb = blockIdx.x << 7;
    const int cb = blockIdx.y << 7;

    const int sr  = t >> 1;          // A staging: row in tile
    const int sk8 = (t & 1) << 3;    // A staging: k offset (0/8)
    const int bkr = t >> 4;          // B staging: k row
    const int bc8 = (t & 15) << 3;   // B staging: col offset

    const float* Ap = A + (size_t)(rb + sr) * lda + sk8;
    const float* Bp = B + (size_t)bkr * ldb + cb + bc8;

    float acc[8][8];
#pragma unroll
    for (int i = 0; i < 8; ++i)
#pragma unroll
        for (int j = 0; j < 8; ++j) acc[i][j] = 0.0f;

    float4 a0 = *(const float4*)Ap;
    float4 a1 = *(const float4*)(Ap + 4);
    float4 b0 = *(const float4*)Bp;
    float4 b1 = *(const float4*)(Bp + 4);

    for (int kb = 0; kb < Kd; kb += 16) {
        __syncthreads();
        As[sk8 + 0][sr] = a0.x; As[sk8 + 1][sr] = a0.y;
        As[sk8 + 2][sr] = a0.z; As[sk8 + 3][sr] = a0.w;
        As[sk8 + 4][sr] = a1.x; As[sk8 + 5][sr] = a1.y;
        As[sk8 + 6][sr] = a1.z; As[sk8 + 7][sr] = a1.w;
        *(float4*)&Bs[bkr][bc8]     = b0;
        *(float4*)&Bs[bkr][bc8 + 4] = b1;
        __syncthreads();
        if (kb + 16 < Kd) {     // prefetch next tiles while computing
            a0 = *(const float4*)(Ap + kb + 16);
            a1 = *(const float4*)(Ap + kb + 20);
            b0 = *(const float4*)(Bp + (size_t)(kb + 16) * ldb);
            b1 = *(const float4*)(Bp + (size_t)(kb + 16) * ldb + 4);
        }
#pragma unroll
        for (int kk = 0; kk < 16; ++kk) {
            float a[8], b[8];
            *(float4*)&a[0] = *(const float4*)&As[kk][ty * 8];
            *(float4*)&a[4] = *(const float4*)&As[kk][ty * 8 + 4];
            *(float4*)&b[0] = *(const float4*)&Bs[kk][tx * 8];
            *(float4*)&b[4] = *(const float4*)&Bs[kk][tx * 8 + 4];
#pragma unroll
            for (int i = 0; i < 8; ++i)
#pragma unroll
                for (int j = 0; j < 8; ++j)
                    acc[i][j] += a[i] * b[j];
        }
    }

    float bb[8];
#pragma unroll
    for (int j = 0; j < 8; ++j) bb[j] = bias[cb + tx * 8 + j];

#pragma unroll
    for (int i = 0; i < 8; ++i) {
        const size_t off = (size_t)(rb + ty * 8 + i) * ldc + cb + tx * 8;
        *(float4*)&C[off]     = make_float4(acc[i][0] + bb[0], acc[i][1] + bb[1],
                                            acc[i][2] + bb[2], acc[i][3] + bb[3]);
        *(float4*)&C[off + 4] = make_float4(acc[i][4] + bb[4], acc[i][5] + bb[5],
                                            acc[i][6] + bb[6], acc[i][7] + bb[7]);
    }
}

// per-row squared norm (rows of length 256): one wave per row, 4 rows/block
__global__ __launch_bounds__(256)
void rowsq_kernel(const float* __restrict__ X, float* __restrict__ s2)
{
    const int t = threadIdx.x;
    const int row = (blockIdx.x << 2) + (t >> 6);
    const int lane = t & 63;
    const float4 v = *(const float4*)(X + (size_t)row * DB + (lane << 2));
    float s = v.x * v.x + v.y * v.y + v.z * v.z + v.w * v.w;
#pragma unroll
    for (int m = 32; m >= 1; m >>= 1) s += __shfl_xor(s, m, 64);
    if (lane == 0) s2[row] = s;
}

__global__ void init_keys(u64* __restrict__ keys)
{
    keys[(blockIdx.x << 8) + threadIdx.x] = ~0ull;
}

// fused scores d = (z2 + e2) - 2*z.e  + argmin via packed u64 atomicMin.
// grid = (M/128 row tiles, K/128 code tiles)
__global__ __launch_bounds__(256)
void score_kernel(const float* __restrict__ Z, const float* __restrict__ E,
                  const float* __restrict__ e2, const float* __restrict__ z2,
                  u64* __restrict__ keys)
{
    __shared__ float Zs[16][132];
    __shared__ float Es[16][132];
    const int t = threadIdx.x;
    const int w = t >> 6, lane = t & 63;
    const int tx = (lane & 7) | ((w & 1) << 3);
    const int ty = ((lane >> 3) & 7) | ((w >> 1) << 3);
    const int ltx = lane & 7;
    const int rb = blockIdx.x << 7;
    const int cb = blockIdx.y << 7;

    const int sr  = t >> 1;
    const int sk8 = (t & 1) << 3;

    const float* Zp = Z + (size_t)(rb + sr) * DB + sk8;
    const float* Ep = E + (size_t)(cb + sr) * DB + sk8;

    float acc[8][8];
#pragma unroll
    for (int i = 0; i < 8; ++i)
#pragma unroll
        for (int j = 0; j < 8; ++j) acc[i][j] = 0.0f;

    float4 z0 = *(const float4*)Zp;
    float4 z1 = *(const float4*)(Zp + 4);
    float4 e0 = *(const float4*)Ep;
    float4 e1 = *(const float4*)(Ep + 4);

    for (int kb = 0; kb < DB; kb += 16) {
        __syncthreads();
        Zs[sk8 + 0][sr] = z0.x; Zs[sk8 + 1][sr] = z0.y;
        Zs[sk8 + 2][sr] = z0.z; Zs[sk8 + 3][sr] = z0.w;
        Zs[sk8 + 4][sr] = z1.x; Zs[sk8 + 5][sr] = z1.y;
        Zs[sk8 + 6][sr] = z1.z; Zs[sk8 + 7][sr] = z1.w;
        Es[sk8 + 0][sr] = e0.x; Es[sk8 + 1][sr] = e0.y;
        Es[sk8 + 2][sr] = e0.z; Es[sk8 + 3][sr] = e0.w;
        Es[sk8 + 4][sr] = e1.x; Es[sk8 + 5][sr] = e1.y;
        Es[sk8 + 6][sr] = e1.z; Es[sk8 + 7][sr] = e1.w;
        __syncthreads();
        if (kb + 16 < DB) {
            z0 = *(const float4*)(Zp + kb + 16);
            z1 = *(const float4*)(Zp + kb + 20);
            e0 = *(const float4*)(Ep + kb + 16);
            e1 = *(const float4*)(Ep + kb + 20);
        }
#pragma unroll
        for (int kk = 0; kk < 16; ++kk) {
            float a[8], b[8];
            *(float4*)&a[0] = *(const float4*)&Zs[kk][ty * 8];
            *(float4*)&a[4] = *(const float4*)&Zs[kk][ty * 8 + 4];
            *(float4*)&b[0] = *(const float4*)&Es[kk][tx * 8];
            *(float4*)&b[4] = *(const float4*)&Es[kk][tx * 8 + 4];
#pragma unroll
            for (int i = 0; i < 8; ++i)
#pragma unroll
                for (int j = 0; j < 8; ++j)
                    acc[i][j] += a[i] * b[j];
        }
    }

    float e2v[8];
#pragma unroll
    for (int j = 0; j < 8; ++j) e2v[j] = e2[cb + tx * 8 + j];

#pragma unroll
    for (int i = 0; i < 8; ++i) {
        const float z2v = z2[rb + ty * 8 + i];
        u64 key = ~0ull;
#pragma unroll
        for (int j = 0; j < 8; ++j) {
            // mirror np: (z2 + e2) rounded, minus (2*dot) [exact x2], rounded
            const float d = (z2v + e2v[j]) - 2.0f * acc[i][j];
            const u64 k = ((u64)ford(d) << 32) | (u32)(cb + tx * 8 + j);
            key = (k < key) ? k : key;   // tie -> smaller code (first occurrence)
        }
#pragma unroll
        for (int m = 1; m <= 4; m <<= 1) {
            const u64 o = shfl_xor_u64(key, m);
            key = (o < key) ? o : key;
        }
        if (ltx == 0) atomicMin(&keys[rb + ty * 8 + i], key);
    }
}

// decode argmin: bneck (fp32 index), qidx (int), reg_z = emb[idx] (fp32 row copy)
__global__ __launch_bounds__(256)
void finalize_kernel(const u64* __restrict__ keys, const float* __restrict__ E,
                     float* __restrict__ bneck, float* __restrict__ regz,
                     int* __restrict__ qidx)
{
    const int t = threadIdx.x;
    const int row = (blockIdx.x << 2) + (t >> 6);
    const int lane = t & 63;
    const u64 key = keys[row];
    const u32 idx = (u32)(key & 0xFFFFFFFFull) & (KCODES - 1);  // clamp: no wild gathers
    if (lane == 0) {
        qidx[row] = (int)idx;
        bneck[row] = (float)idx;
    }
    const float4 v = *(const float4*)(E + (size_t)idx * DB + (lane << 2));
    *(float4*)(regz + (size_t)row * DB + (lane << 2)) = v;
}

// x_hat = emb[qidx[row]] @ W_out(f32) + b_out; M=32768, K=256, N=1024
__global__ __launch_bounds__(256)
void xhat_gemm(const int* __restrict__ qidx, const float* __restrict__ E,
               const float* __restrict__ B, const float* __restrict__ bias,
               float* __restrict__ C)
{
    __shared__ float As[16][132];
    __shared__ float Bs[16][132];
    const int t = threadIdx.x;
    const int w = t >> 6, lane = t & 63;
    const int tx = (lane & 7) | ((w & 1) << 3);
    const int ty = ((lane >> 3) & 7) | ((w >> 1) << 3);
    const int rb = blockIdx.x << 7;
    const int cb = blockIdx.y << 7;

    const int sr  = t >> 1;
    const int sk8 = (t & 1) << 3;
    const int bkr = t >> 4;
    const int bc8 = (t & 15) << 3;

    const int aidx = qidx[rb + sr] & (KCODES - 1);  // clamp: no wild gathers
    const float* Ap = E + (size_t)aidx * DB + sk8;  // fp32 emb row gather
    const float* Bp = B + (size_t)bkr * DIN + cb + bc8;

    float acc[8][8];
#pragma unroll
    for (int i = 0; i < 8; ++i)
#pragma unroll
        for (int j = 0; j < 8; ++j) acc[i][j] = 0.0f;

    float4 a0 = *(const float4*)Ap;
    float4 a1 = *(const float4*)(Ap + 4);
    float4 b0 = *(const float4*)Bp;
    float4 b1 = *(const float4*)(Bp + 4);

    for (int kb = 0; kb < DB; kb += 16) {
        __syncthreads();
        As[sk8 + 0][sr] = a0.x; As[sk8 + 1][sr] = a0.y;
        As[sk8 + 2][sr] = a0.z; As[sk8 + 3][sr] = a0.w;
        As[sk8 + 4][sr] = a1.x; As[sk8 + 5][sr] = a1.y;
        As[sk8 + 6][sr] = a1.z; As[sk8 + 7][sr] = a1.w;
        *(float4*)&Bs[bkr][bc8]     = b0;
        *(float4*)&Bs[bkr][bc8 + 4] = b1;
        __syncthreads();
        if (kb + 16 < DB) {
            a0 = *(const float4*)(Ap + kb + 16);
            a1 = *(const float4*)(Ap + kb + 20);
            b0 = *(const float4*)(Bp + (size_t)(kb + 16) * DIN);
            b1 = *(const float4*)(Bp + (size_t)(kb + 16) * DIN + 4);
        }
#pragma unroll
        for (int kk = 0; kk < 16; ++kk) {
            float a[8], b[8];
            *(float4*)&a[0] = *(const float4*)&As[kk][ty * 8];
            *(float4*)&a[4] = *(const float4*)&As[kk][ty * 8 + 4];
            *(float4*)&b[0] = *(const float4*)&Bs[kk][tx * 8];
            *(float4*)&b[4] = *(const float4*)&Bs[kk][tx * 8 + 4];
#pragma unroll
            for (int i = 0; i < 8; ++i)
#pragma unroll
                for (int j = 0; j < 8; ++j)
                    acc[i][j] += a[i] * b[j];
        }
    }

    float bb[8];
#pragma unroll
    for (int j = 0; j < 8; ++j) bb[j] = bias[cb + tx * 8 + j];

#pragma unroll
    for (int i = 0; i < 8; ++i) {
        const size_t off = (size_t)(rb + ty * 8 + i) * DIN + cb + tx * 8;
        *(float4*)&C[off]     = make_float4(acc[i][0] + bb[0], acc[i][1] + bb[1],
                                            acc[i][2] + bb[2], acc[i][3] + bb[3]);
        *(float4*)&C[off + 4] = make_float4(acc[i][4] + bb[4], acc[i][5] + bb[5],
                                            acc[i][6] + bb[6], acc[i][7] + bb[7]);
    }
}

extern "C" void kernel_launch(void* const* d_in, const int* in_sizes, int n_in,
                              void* d_out, int out_size, void* d_ws, size_t ws_size,
                              hipStream_t stream)
{
    const float* x        = (const float*)d_in[0];
    const float* W_in     = (const float*)d_in[1];
    const float* b_in     = (const float*)d_in[2];
    const float* W_out    = (const float*)d_in[3];
    const float* b_out    = (const float*)d_in[4];
    const float* codebook = (const float*)d_in[5];
    const float* W_proj   = (const float*)d_in[6];
    const float* b_proj   = (const float*)d_in[7];

    // fp32 output layout, return order (x_hat, bneck, z, emb, reg_z)
    float* out   = (float*)d_out;
    float* xhat  = out;                   // 33,554,432
    float* bneck = out + 33554432;        //     32,768
    float* z     = out + 33587200;        //  8,388,608
    float* emb   = out + 41975808;        //  4,194,304
    float* regz  = out + 46170112;        //  8,388,608

    // d_ws: small buffers only (576 KB)
    char* ws = (char*)d_ws;
    float* e2   = (float*)ws;                 //  64 KB
    float* z2   = (float*)(ws + 65536);       // 128 KB
    u64*   keys = (u64*)  (ws + 196608);      // 256 KB
    int*   qidx = (int*)  (ws + 458752);      // 128 KB

    // 1. emb = codebook @ W_proj + b_proj
    sgemm_f32<<<dim3(128, 2), 256, 0, stream>>>(codebook, DB, W_proj, DB, b_proj,
                                                emb, DB, DB);
    // 2. per-code squared norms
    rowsq_kernel<<<KCODES / 4, 256, 0, stream>>>(emb, e2);
    // 3. z = x @ W_in + b_in
    sgemm_f32<<<dim3(256, 2), 256, 0, stream>>>(x, DIN, W_in, DB, b_in,
                                                z, DB, DIN);
    // 4. per-row squared norms of z
    rowsq_kernel<<<M_ROWS / 4, 256, 0, stream>>>(z, z2);
    // 5. reset argmin keys (ws is re-poisoned each launch)
    init_keys<<<M_ROWS / 256, 256, 0, stream>>>(keys);
    // 6. fused distance GEMM + argmin
    score_kernel<<<dim3(M_ROWS / 128, KCODES / 128), 256, 0, stream>>>(z, emb, e2, z2, keys);
    // 7. decode indices, write bneck + reg_z
    finalize_kernel<<<M_ROWS / 4, 256, 0, stream>>>(keys, emb, bneck, regz, qidx);
    // 8. x_hat = emb[qidx] @ W_out + b_out
    xhat_gemm<<<dim3(256, 8), 256, 0, stream>>>(qidx, emb, W_out, b_out, xhat);
}